// Round 1
// baseline (479.663 us; speedup 1.0000x reference)
//
#include <hip/hip_runtime.h>
#include <hip/hip_bf16.h>

#define N_Z 16384
#define M_E 4096
#define DIM 256

typedef __bf16 bf16x8 __attribute__((ext_vector_type(8)));
typedef float f32x4 __attribute__((ext_vector_type(4)));

__device__ __forceinline__ unsigned short f2bf(float f) {
  unsigned u = __float_as_uint(f);
  u = (u + 0x7FFFu + ((u >> 16) & 1u)) >> 16;
  return (unsigned short)u;
}

__device__ __forceinline__ void gl2lds16(const void* g, void* s) {
  __builtin_amdgcn_global_load_lds(
      (const __attribute__((address_space(1))) unsigned*)g,
      (__attribute__((address_space(3))) unsigned*)s, 16, 0, 0);
}

// ---------------- init: d2min = +inf bits, sums = 0 ----------------
__global__ void init_kernel(unsigned* __restrict__ d2min, float* __restrict__ sums) {
  int i = blockIdx.x * blockDim.x + threadIdx.x;
  if (i < M_E) d2min[i] = 0x7F800000u;  // +inf
  if (i == 0) sums[0] = 0.0f;
}

// ---------------- f32 -> bf16 convert (RNE), vectorized ----------------
__global__ void convert_kernel(const float* __restrict__ z, const float* __restrict__ e,
                               unsigned short* __restrict__ zb, unsigned short* __restrict__ eb) {
  const int NZ4 = N_Z * DIM / 4;
  const int NE4 = M_E * DIM / 4;
  int stride = gridDim.x * blockDim.x;
  for (int i = blockIdx.x * blockDim.x + threadIdx.x; i < NZ4 + NE4; i += stride) {
    const float4* src;
    unsigned short* dst;
    if (i < NZ4) {
      src = (const float4*)z + i;
      dst = zb + (size_t)i * 4;
    } else {
      int j = i - NZ4;
      src = (const float4*)e + j;
      dst = eb + (size_t)j * 4;
    }
    float4 v = *src;
    ushort4 o;
    o.x = f2bf(v.x); o.y = f2bf(v.y); o.z = f2bf(v.z); o.w = f2bf(v.w);
    *(ushort4*)dst = o;
  }
}

// ---------------- row squared-norms: one wave (64 threads) per row ----------------
__global__ void rowsum_kernel(const float* __restrict__ z, const float* __restrict__ e,
                              float* __restrict__ z2, float* __restrict__ e2) {
  int r = blockIdx.x;
  int l = threadIdx.x;
  const float* src = (r < N_Z) ? (z + (size_t)r * DIM) : (e + (size_t)(r - N_Z) * DIM);
  float4 v = ((const float4*)src)[l];
  float s = v.x * v.x + v.y * v.y + v.z * v.z + v.w * v.w;
#pragma unroll
  for (int off = 32; off; off >>= 1) s += __shfl_down(s, off);
  if (l == 0) {
    if (r < N_Z) z2[r] = s;
    else e2[r - N_Z] = s;
  }
}

// ---------------- fused bf16 GEMM (z . e^T) + min over n, per m ----------------
// 128x128 tile, 4 waves (2x2), BK=32, mfma_f32_16x16x32_bf16, m97-style staging.
__global__ __launch_bounds__(256, 2) void gemm_min_kernel(
    const unsigned short* __restrict__ zb, const unsigned short* __restrict__ eb,
    const float* __restrict__ z2, const float* __restrict__ e2,
    unsigned* __restrict__ d2min) {
  __shared__ __align__(16) unsigned short lA[128 * 32];
  __shared__ __align__(16) unsigned short lB[128 * 32];

  const int t = threadIdx.x;
  const int w = t >> 6;
  const int l = t & 63;
  const int wr = w >> 1, wc = w & 1;  // wave position in 2x2 -> 64x64 subtile
  const int tileM = blockIdx.x * 128;
  const int tileN = blockIdx.y * 128;
  const int l15 = l & 15;
  const int kgr = l >> 4;  // 0..3

  f32x4 acc[4][4];
#pragma unroll
  for (int i = 0; i < 4; ++i)
#pragma unroll
    for (int j = 0; j < 4; ++j) acc[i][j] = (f32x4){0.f, 0.f, 0.f, 0.f};

#pragma unroll 1
  for (int k0 = 0; k0 < DIM; k0 += 32) {
    // stage A (z tile) and B (e tile): 8KB each, 16B/lane chunks.
    // chunk c = i*256 + t ; row = c>>2 ; kchunk = c&3 ; lds byte off = c*16 (linear)
#pragma unroll
    for (int i = 0; i < 2; ++i) {
      int c = i * 256 + t;
      int row = c >> 2;
      int kc = c & 3;
      int ldsbase = (i * 256 + (t & ~63)) * 8;  // wave-uniform, elements
      gl2lds16(zb + (size_t)(tileN + row) * DIM + (k0 + kc * 8), &lA[ldsbase]);
      gl2lds16(eb + (size_t)(tileM + row) * DIM + (k0 + kc * 8), &lB[ldsbase]);
    }
    __syncthreads();

    bf16x8 a[4], b[4];
#pragma unroll
    for (int mi = 0; mi < 4; ++mi)
      a[mi] = *(const bf16x8*)&lA[(wr * 64 + mi * 16 + l15) * 32 + kgr * 8];
#pragma unroll
    for (int ni = 0; ni < 4; ++ni)
      b[ni] = *(const bf16x8*)&lB[(wc * 64 + ni * 16 + l15) * 32 + kgr * 8];
#pragma unroll
    for (int mi = 0; mi < 4; ++mi)
#pragma unroll
      for (int ni = 0; ni < 4; ++ni)
        acc[mi][ni] = __builtin_amdgcn_mfma_f32_16x16x32_bf16(a[mi], b[ni], acc[mi][ni], 0, 0, 0);
    __syncthreads();
  }

  // epilogue: d2[n,m] = z2[n] + e2[m] - 2*S ; min over the 128 n-rows of this tile
  float* z2s = (float*)lA;  // reuse LDS
  if (t < 128) z2s[t] = z2[tileN + t];
  __syncthreads();

#pragma unroll
  for (int ni = 0; ni < 4; ++ni) {
    float v = 3.4e38f;
#pragma unroll
    for (int mi = 0; mi < 4; ++mi)
#pragma unroll
      for (int r = 0; r < 4; ++r) {
        int rloc = wr * 64 + mi * 16 + kgr * 4 + r;  // C/D: col=l&15, row=(l>>4)*4+r
        v = fminf(v, z2s[rloc] - 2.0f * acc[mi][ni][r]);
      }
    // reduce across lanes sharing the same column (l15): kgr = 0..3 live in l^16, l^32
    v = fminf(v, __shfl_xor(v, 16));
    v = fminf(v, __shfl_xor(v, 32));
    if (l < 16) {
      int m = tileM + wc * 64 + ni * 16 + l;
      float d2 = v + e2[m];  // >= 0, so uint-bit ordering == float ordering
      atomicMin(&d2min[m], __float_as_uint(d2));
    }
  }
}

// ---------------- wise_min: per-column bitonic sort + binary search ----------------
__global__ __launch_bounds__(1024) void wise_kernel(const float* __restrict__ z,
                                                    const float* __restrict__ e,
                                                    float* __restrict__ wise_sum) {
  __shared__ float s[N_Z];  // 64 KiB
  const int d = blockIdx.x;
  const int t = threadIdx.x;

  for (int n = t; n < N_Z; n += 1024) s[n] = z[(size_t)n * DIM + d];
  __syncthreads();

  // bitonic sort ascending
  for (unsigned k = 2; k <= N_Z; k <<= 1) {
    for (unsigned j = k >> 1; j; j >>= 1) {
      for (unsigned i = t; i < N_Z; i += 1024) {
        unsigned ixj = i ^ j;
        if (ixj > i) {
          float a = s[i], b = s[ixj];
          bool asc = (i & k) == 0;
          if (asc ? (a > b) : (a < b)) {
            s[i] = b;
            s[ixj] = a;
          }
        }
      }
      __syncthreads();
    }
  }

  // nearest-neighbor search for each e[m][d]
  float local = 0.0f;
  for (int m = t; m < M_E; m += 1024) {
    float ev = e[(size_t)m * DIM + d];
    int lo = 0, hi = N_Z;
    while (lo < hi) {
      int mid = (lo + hi) >> 1;
      if (s[mid] < ev) lo = mid + 1;
      else hi = mid;
    }
    float best = 3.4e38f;
    if (lo < N_Z) {
      float dd = s[lo] - ev;
      best = dd * dd;
    }
    if (lo > 0) {
      float dd = s[lo - 1] - ev;
      best = fminf(best, dd * dd);
    }
    local += best;
  }
#pragma unroll
  for (int off = 32; off; off >>= 1) local += __shfl_down(local, off);
  if ((t & 63) == 0) atomicAdd(wise_sum, local);
}

// ---------------- final reduce ----------------
__global__ void final_kernel(const unsigned* __restrict__ d2min, const float* __restrict__ sums,
                             float* __restrict__ out) {
  __shared__ float red[4];
  int t = threadIdx.x;
  float s = 0.0f;
  for (int m = t; m < M_E; m += 256) s += __uint_as_float(d2min[m]);
#pragma unroll
  for (int off = 32; off; off >>= 1) s += __shfl_down(s, off);
  if ((t & 63) == 0) red[t >> 6] = s;
  __syncthreads();
  if (t == 0) {
    float tot = red[0] + red[1] + red[2] + red[3];
    out[0] = tot / (float)M_E;
    out[1] = sums[0] / ((float)M_E * (float)DIM);
  }
}

extern "C" void kernel_launch(void* const* d_in, const int* in_sizes, int n_in,
                              void* d_out, int out_size, void* d_ws, size_t ws_size,
                              hipStream_t stream) {
  const float* z = (const float*)d_in[0];
  const float* e = (const float*)d_in[1];
  float* out = (float*)d_out;

  char* ws = (char*)d_ws;
  unsigned short* zb = (unsigned short*)ws;                      // 8 MiB
  unsigned short* eb = (unsigned short*)(ws + 8388608);          // 2 MiB
  float* z2 = (float*)(ws + 10485760);                           // 64 KiB
  float* e2 = (float*)(ws + 10551296);                           // 16 KiB
  unsigned* d2min = (unsigned*)(ws + 10567680);                  // 16 KiB
  float* sums = (float*)(ws + 10584064);                         // 4 B

  init_kernel<<<16, 256, 0, stream>>>(d2min, sums);
  convert_kernel<<<2048, 256, 0, stream>>>(z, e, zb, eb);
  rowsum_kernel<<<N_Z + M_E, 64, 0, stream>>>(z, e, z2, e2);
  gemm_min_kernel<<<dim3(M_E / 128, N_Z / 128), 256, 0, stream>>>(zb, eb, z2, e2, d2min);
  wise_kernel<<<DIM, 1024, 0, stream>>>(z, e, sums);
  final_kernel<<<1, 256, 0, stream>>>(d2min, sums, out);
}

// Round 2
// 209.853 us; speedup vs baseline: 2.2857x; 2.2857x over previous
//
#include <hip/hip_runtime.h>
#include <hip/hip_bf16.h>

#define N_Z 16384
#define M_E 4096
#define DIM 256
#define NB 2048                      // value buckets for wise kernel
#define BMIN (-6.0f)
#define BSCALE ((float)NB / 12.0f)   // buckets per unit
#define BW (12.0f / (float)NB)       // bucket width (exact: 3*2^-9)

typedef __bf16 bf16x8 __attribute__((ext_vector_type(8)));
typedef float f32x4 __attribute__((ext_vector_type(4)));

__device__ __forceinline__ unsigned short f2bf(float f) {
  unsigned u = __float_as_uint(f);
  u = (u + 0x7FFFu + ((u >> 16) & 1u)) >> 16;
  return (unsigned short)u;
}

__device__ __forceinline__ void gl2lds16(const void* g, void* s) {
  __builtin_amdgcn_global_load_lds(
      (const __attribute__((address_space(1))) unsigned*)g,
      (__attribute__((address_space(3))) unsigned*)s, 16, 0, 0);
}

// order-preserving float<->uint map (works for negatives)
__device__ __forceinline__ unsigned fmap(float f) {
  unsigned u = __float_as_uint(f);
  return (u & 0x80000000u) ? ~u : (u | 0x80000000u);
}
__device__ __forceinline__ float funmap(unsigned u) {
  return __uint_as_float((u & 0x80000000u) ? (u ^ 0x80000000u) : ~u);
}
__device__ __forceinline__ int bucketOf(float v) {
  int b = (int)((v - BMIN) * BSCALE);
  return min(max(b, 0), NB - 1);
}

// ---------------- init: d2min = +inf bits, sums = 0 ----------------
__global__ void init_kernel(unsigned* __restrict__ d2min, float* __restrict__ sums) {
  int i = blockIdx.x * blockDim.x + threadIdx.x;
  if (i < M_E) d2min[i] = 0x7F800000u;  // +inf
  if (i == 0) sums[0] = 0.0f;
}

// ---------------- f32 -> bf16 convert (RNE), vectorized ----------------
__global__ void convert_kernel(const float* __restrict__ z, const float* __restrict__ e,
                               unsigned short* __restrict__ zb, unsigned short* __restrict__ eb) {
  const int NZ4 = N_Z * DIM / 4;
  const int NE4 = M_E * DIM / 4;
  int stride = gridDim.x * blockDim.x;
  for (int i = blockIdx.x * blockDim.x + threadIdx.x; i < NZ4 + NE4; i += stride) {
    const float4* src;
    unsigned short* dst;
    if (i < NZ4) {
      src = (const float4*)z + i;
      dst = zb + (size_t)i * 4;
    } else {
      int j = i - NZ4;
      src = (const float4*)e + j;
      dst = eb + (size_t)j * 4;
    }
    float4 v = *src;
    ushort4 o;
    o.x = f2bf(v.x); o.y = f2bf(v.y); o.z = f2bf(v.z); o.w = f2bf(v.w);
    *(ushort4*)dst = o;
  }
}

// ---------------- row squared-norms: one wave (64 threads) per row ----------------
__global__ void rowsum_kernel(const float* __restrict__ z, const float* __restrict__ e,
                              float* __restrict__ z2, float* __restrict__ e2) {
  int r = blockIdx.x;
  int l = threadIdx.x;
  const float* src = (r < N_Z) ? (z + (size_t)r * DIM) : (e + (size_t)(r - N_Z) * DIM);
  float4 v = ((const float4*)src)[l];
  float s = v.x * v.x + v.y * v.y + v.z * v.z + v.w * v.w;
#pragma unroll
  for (int off = 32; off; off >>= 1) s += __shfl_down(s, off);
  if (l == 0) {
    if (r < N_Z) z2[r] = s;
    else e2[r - N_Z] = s;
  }
}

// ---------------- transpose [R, 256] -> [256, R] ----------------
__global__ void transpose_kernel(const float* __restrict__ in, float* __restrict__ out, int R) {
  __shared__ float tile[32][33];
  int c0 = blockIdx.y * 32;
  int r0 = blockIdx.x * 32;
  int tx = threadIdx.x, ty = threadIdx.y;  // 32 x 8
#pragma unroll
  for (int i = 0; i < 4; ++i)
    tile[ty + 8 * i][tx] = in[(size_t)(r0 + ty + 8 * i) * DIM + c0 + tx];
  __syncthreads();
#pragma unroll
  for (int i = 0; i < 4; ++i)
    out[(size_t)(c0 + ty + 8 * i) * R + r0 + tx] = tile[tx][ty + 8 * i];
}

// ---------------- fused bf16 GEMM (z . e^T) + min over n, per m ----------------
__global__ __launch_bounds__(256, 2) void gemm_min_kernel(
    const unsigned short* __restrict__ zb, const unsigned short* __restrict__ eb,
    const float* __restrict__ z2, const float* __restrict__ e2,
    unsigned* __restrict__ d2min) {
  __shared__ __align__(16) unsigned short lA[128 * 32];
  __shared__ __align__(16) unsigned short lB[128 * 32];

  const int t = threadIdx.x;
  const int w = t >> 6;
  const int l = t & 63;
  const int wr = w >> 1, wc = w & 1;
  const int tileM = blockIdx.x * 128;
  const int tileN = blockIdx.y * 128;
  const int l15 = l & 15;
  const int kgr = l >> 4;

  f32x4 acc[4][4];
#pragma unroll
  for (int i = 0; i < 4; ++i)
#pragma unroll
    for (int j = 0; j < 4; ++j) acc[i][j] = (f32x4){0.f, 0.f, 0.f, 0.f};

#pragma unroll 1
  for (int k0 = 0; k0 < DIM; k0 += 32) {
#pragma unroll
    for (int i = 0; i < 2; ++i) {
      int c = i * 256 + t;
      int row = c >> 2;
      int kc = c & 3;
      int ldsbase = (i * 256 + (t & ~63)) * 8;
      gl2lds16(zb + (size_t)(tileN + row) * DIM + (k0 + kc * 8), &lA[ldsbase]);
      gl2lds16(eb + (size_t)(tileM + row) * DIM + (k0 + kc * 8), &lB[ldsbase]);
    }
    __syncthreads();

    bf16x8 a[4], b[4];
#pragma unroll
    for (int mi = 0; mi < 4; ++mi)
      a[mi] = *(const bf16x8*)&lA[(wr * 64 + mi * 16 + l15) * 32 + kgr * 8];
#pragma unroll
    for (int ni = 0; ni < 4; ++ni)
      b[ni] = *(const bf16x8*)&lB[(wc * 64 + ni * 16 + l15) * 32 + kgr * 8];
#pragma unroll
    for (int mi = 0; mi < 4; ++mi)
#pragma unroll
      for (int ni = 0; ni < 4; ++ni)
        acc[mi][ni] = __builtin_amdgcn_mfma_f32_16x16x32_bf16(a[mi], b[ni], acc[mi][ni], 0, 0, 0);
    __syncthreads();
  }

  float* z2s = (float*)lA;
  if (t < 128) z2s[t] = z2[tileN + t];
  __syncthreads();

#pragma unroll
  for (int ni = 0; ni < 4; ++ni) {
    float v = 3.4e38f;
#pragma unroll
    for (int mi = 0; mi < 4; ++mi)
#pragma unroll
      for (int r = 0; r < 4; ++r) {
        int rloc = wr * 64 + mi * 16 + kgr * 4 + r;
        v = fminf(v, z2s[rloc] - 2.0f * acc[mi][ni][r]);
      }
    v = fminf(v, __shfl_xor(v, 16));
    v = fminf(v, __shfl_xor(v, 32));
    if (l < 16) {
      int m = tileM + wc * 64 + ni * 16 + l;
      float d2 = v + e2[m];
      atomicMin(&d2min[m], __float_as_uint(d2));
    }
  }
}

// ---------------- wise_min: bucket min/max + e counting-sort, no full sort ----------------
// One block per dim d. Exact: cross-bucket nearest is bucket min/max; own-bucket
// interiors handled by a z-driven atomicMin pass.
__global__ __launch_bounds__(1024) void wise_kernel(
    const float* __restrict__ z, const float* __restrict__ e,
    const float* __restrict__ zT, const float* __restrict__ eT,
    int transposed, float* __restrict__ wise_sum) {
  __shared__ unsigned zminU[NB];
  __shared__ unsigned zmaxU[NB];
  __shared__ unsigned eoff[NB];
  __shared__ float esorted[M_E];
  __shared__ unsigned eres[M_E];
  __shared__ unsigned wsum[16];

  const int d = blockIdx.x;
  const int t = threadIdx.x;

  for (int i = t; i < NB; i += 1024) {
    zminU[i] = 0xFFFFFFFFu;
    zmaxU[i] = 0u;
    eoff[i] = 0u;
  }
  __syncthreads();

  // --- load z column (16 per thread), bucket min/max ---
  float zv[16];
  if (transposed) {
    const float4* p = (const float4*)(zT + (size_t)d * N_Z);
#pragma unroll
    for (int i = 0; i < 4; ++i) {
      float4 v = p[i * 1024 + t];
      zv[i * 4 + 0] = v.x; zv[i * 4 + 1] = v.y; zv[i * 4 + 2] = v.z; zv[i * 4 + 3] = v.w;
    }
  } else {
#pragma unroll
    for (int i = 0; i < 16; ++i) zv[i] = z[(size_t)(i * 1024 + t) * DIM + d];
  }
#pragma unroll
  for (int i = 0; i < 16; ++i) {
    int b = bucketOf(zv[i]);
    unsigned u = fmap(zv[i]);
    atomicMin(&zminU[b], u);
    atomicMax(&zmaxU[b], u);
  }

  // --- load e column (4 per thread), histogram ---
  float ev4[4];
  int ebk[4];
  if (transposed) {
    float4 v = ((const float4*)(eT + (size_t)d * M_E))[t];
    ev4[0] = v.x; ev4[1] = v.y; ev4[2] = v.z; ev4[3] = v.w;
  } else {
#pragma unroll
    for (int i = 0; i < 4; ++i) ev4[i] = e[(size_t)(t * 4 + i) * DIM + d];
  }
#pragma unroll
  for (int i = 0; i < 4; ++i) {
    ebk[i] = bucketOf(ev4[i]);
    atomicAdd(&eoff[ebk[i]], 1u);
  }
  __syncthreads();

  // --- exclusive prefix sum over eoff[NB], 2 buckets/thread ---
  unsigned c0 = eoff[2 * t], c1 = eoff[2 * t + 1];
  unsigned ts = c0 + c1;
  unsigned s = ts;
#pragma unroll
  for (int o = 1; o < 64; o <<= 1) {
    unsigned v = __shfl_up(s, o);
    if ((t & 63) >= o) s += v;
  }
  if ((t & 63) == 63) wsum[t >> 6] = s;
  __syncthreads();
  if (t == 0) {
    unsigned acc = 0;
#pragma unroll
    for (int i = 0; i < 16; ++i) { unsigned v = wsum[i]; wsum[i] = acc; acc += v; }
  }
  __syncthreads();
  unsigned texcl = wsum[t >> 6] + (s - ts);
  eoff[2 * t] = texcl;
  eoff[2 * t + 1] = texcl + c0;
  __syncthreads();

  // --- scatter e by bucket (cursor in place; after, eoff[b] = end of b) ---
#pragma unroll
  for (int i = 0; i < 4; ++i) {
    unsigned pos = atomicAdd(&eoff[ebk[i]], 1u);
    esorted[pos] = ev4[i];
  }
  __syncthreads();

  // --- pass A: per query, cross-bucket candidates via zmin/zmax expansion ---
#pragma unroll
  for (int q = 0; q < 4; ++q) {
    int idx = q * 1024 + t;
    float ev = esorted[idx];
    int b0 = bucketOf(ev);
    float best2 = 3.4e38f;
    unsigned mn = zminU[b0], mx = zmaxU[b0];
    if (mn != 0xFFFFFFFFu) {
      float dd = funmap(mn) - ev;
      best2 = dd * dd;
      dd = funmap(mx) - ev;
      best2 = fminf(best2, dd * dd);
    }
    for (int r = 1; r < NB; ++r) {
      int bl = b0 - r, br = b0 + r;
      float edgeL = BMIN + (float)(b0 - r + 1) * BW;
      float edgeR = BMIN + (float)(b0 + r) * BW;
      float dL = ev - edgeL;
      float dR = edgeR - ev;
      bool doL = (bl >= 0) && (dL * dL < best2);
      bool doR = (br < NB) && (dR * dR < best2);
      if (!doL && !doR) break;
      if (doL) {
        unsigned u = zmaxU[bl];
        if (u != 0u) { float dd = funmap(u) - ev; best2 = fminf(best2, dd * dd); }
      }
      if (doR) {
        unsigned u = zminU[br];
        if (u != 0xFFFFFFFFu) { float dd = funmap(u) - ev; best2 = fminf(best2, dd * dd); }
      }
    }
    eres[idx] = __float_as_uint(best2);
  }
  __syncthreads();

  // --- pass B: own-bucket interiors; each z updates e's in its bucket ---
#pragma unroll
  for (int i = 0; i < 16; ++i) {
    int b = bucketOf(zv[i]);
    unsigned s0 = (b == 0) ? 0u : eoff[b - 1];
    unsigned s1 = eoff[b];
    for (unsigned j = s0; j < s1; ++j) {
      float dd = zv[i] - esorted[j];
      atomicMin(&eres[j], __float_as_uint(dd * dd));
    }
  }
  __syncthreads();

  // --- sum ---
  float loc = 0.0f;
  for (int i = t; i < M_E; i += 1024) loc += __uint_as_float(eres[i]);
#pragma unroll
  for (int off = 32; off; off >>= 1) loc += __shfl_down(loc, off);
  if ((t & 63) == 0) atomicAdd(wise_sum, loc);
}

// ---------------- final reduce ----------------
__global__ void final_kernel(const unsigned* __restrict__ d2min, const float* __restrict__ sums,
                             float* __restrict__ out) {
  __shared__ float red[4];
  int t = threadIdx.x;
  float s = 0.0f;
  for (int m = t; m < M_E; m += 256) s += __uint_as_float(d2min[m]);
#pragma unroll
  for (int off = 32; off; off >>= 1) s += __shfl_down(s, off);
  if ((t & 63) == 0) red[t >> 6] = s;
  __syncthreads();
  if (t == 0) {
    float tot = red[0] + red[1] + red[2] + red[3];
    out[0] = tot / (float)M_E;
    out[1] = sums[0] / ((float)M_E * (float)DIM);
  }
}

extern "C" void kernel_launch(void* const* d_in, const int* in_sizes, int n_in,
                              void* d_out, int out_size, void* d_ws, size_t ws_size,
                              hipStream_t stream) {
  const float* z = (const float*)d_in[0];
  const float* e = (const float*)d_in[1];
  float* out = (float*)d_out;

  char* ws = (char*)d_ws;
  unsigned short* zb = (unsigned short*)ws;                      // 8 MiB
  unsigned short* eb = (unsigned short*)(ws + 8388608);          // 2 MiB
  float* z2 = (float*)(ws + 10485760);                           // 64 KiB
  float* e2 = (float*)(ws + 10551296);                           // 16 KiB
  unsigned* d2min = (unsigned*)(ws + 10567680);                  // 16 KiB
  float* sums = (float*)(ws + 10584064);                         // 4 B
  float* zT = (float*)(ws + 11534336);                           // 16 MiB
  float* eT = (float*)(ws + 28311552);                           // 4 MiB
  const size_t WS_NEED = 28311552 + 4194304;
  int transposed = (ws_size >= WS_NEED) ? 1 : 0;

  init_kernel<<<16, 256, 0, stream>>>(d2min, sums);
  convert_kernel<<<2048, 256, 0, stream>>>(z, e, zb, eb);
  rowsum_kernel<<<N_Z + M_E, 64, 0, stream>>>(z, e, z2, e2);
  if (transposed) {
    transpose_kernel<<<dim3(N_Z / 32, DIM / 32), dim3(32, 8), 0, stream>>>(z, zT, N_Z);
    transpose_kernel<<<dim3(M_E / 32, DIM / 32), dim3(32, 8), 0, stream>>>(e, eT, M_E);
  }
  gemm_min_kernel<<<dim3(M_E / 128, N_Z / 128), 256, 0, stream>>>(zb, eb, z2, e2, d2min);
  wise_kernel<<<DIM, 1024, 0, stream>>>(z, e, zT, eT, transposed, sums);
  final_kernel<<<1, 256, 0, stream>>>(d2min, sums, out);
}